// Round 2
// baseline (395.659 us; speedup 1.0000x reference)
//
#include <hip/hip_runtime.h>
#include <math.h>

// Lower-triangle flat index, j <= i
#define LT(i,j) ((i)*((i)+1)/2 + (j))

// reflect index into [0,512) for i in (-512, 1022)
__device__ __forceinline__ int reflect512(int i) {
  int a = (i < 0) ? -i : i;
  int b = 1022 - a;
  return (a < b) ? a : b;
}

// Packed-lower SPD 6x6 -> packed-lower L^{-1} in place. No divides:
// diagonal of L is stored as its reciprocal (v_rsq), which is also M[j][j].
__device__ __forceinline__ void cholinv6(float* a) {
  #pragma unroll
  for (int j = 0; j < 6; ++j) {
    float d = a[LT(j,j)];
    #pragma unroll
    for (int p = 0; p < j; ++p) d -= a[LT(j,p)] * a[LT(j,p)];
    const float rd = __builtin_amdgcn_rsqf(d);   // 1/sqrt(d) = 1/L[j][j]
    a[LT(j,j)] = rd;
    #pragma unroll
    for (int i = j + 1; i < 6; ++i) {
      float s = a[LT(i,j)];
      #pragma unroll
      for (int p = 0; p < j; ++p) s -= a[LT(i,p)] * a[LT(j,p)];
      a[LT(i,j)] = s * rd;                       // L[i][j]
    }
  }
  // In-place lower-triangular inverse (column-major order is in-place safe).
  // a[LT(j,j)] already holds M[j][j] = 1/L[j][j].
  #pragma unroll
  for (int j = 0; j < 6; ++j) {
    #pragma unroll
    for (int i = j + 1; i < 6; ++i) {
      float s = 0.0f;
      #pragma unroll
      for (int p = j; p < i; ++p) s += a[LT(i,p)] * a[LT(p,j)];
      a[LT(i,j)] = -s * a[LT(i,i)];
    }
  }
}

// Accumulate (+/-) one padded row's K window positions into the 90 sums.
template <int R, bool ADD>
__device__ __forceinline__ void row_acc(const float* __restrict__ xb,
                                        const float* __restrict__ yb,
                                        int rowoff, const int* cref,
                                        float* sx, float* sy,
                                        float* sxx, float* syy, float* sxy) {
  constexpr int K = 2 * R + 1;
  constexpr int HW = 512 * 512;
  #pragma unroll
  for (int dx = 0; dx < K; ++dx) {
    const int o = rowoff + cref[dx];
    float xv[6], yv[6];
    #pragma unroll
    for (int c = 0; c < 6; ++c) {
      xv[c] = xb[c * HW + o];
      yv[c] = yb[c * HW + o];
    }
    if (ADD) {
      #pragma unroll
      for (int c = 0; c < 6; ++c) { sx[c] += xv[c]; sy[c] += yv[c]; }
      int t = 0;
      #pragma unroll
      for (int i = 0; i < 6; ++i) {
        #pragma unroll
        for (int j = 0; j <= i; ++j) {
          sxx[t] += xv[i] * xv[j];
          syy[t] += yv[i] * yv[j];
          ++t;
        }
      }
      #pragma unroll
      for (int i = 0; i < 6; ++i)
        #pragma unroll
        for (int j = 0; j < 6; ++j) sxy[i * 6 + j] += xv[i] * yv[j];
    } else {
      #pragma unroll
      for (int c = 0; c < 6; ++c) { sx[c] -= xv[c]; sy[c] -= yv[c]; }
      int t = 0;
      #pragma unroll
      for (int i = 0; i < 6; ++i) {
        #pragma unroll
        for (int j = 0; j <= i; ++j) {
          sxx[t] -= xv[i] * xv[j];
          syy[t] -= yv[i] * yv[j];
          ++t;
        }
      }
      #pragma unroll
      for (int i = 0; i < 6; ++i)
        #pragma unroll
        for (int j = 0; j < 6; ++j) sxy[i * 6 + j] -= xv[i] * yv[j];
    }
  }
}

// Covariances -> Cholesky-inverse -> |diag| mean -> store. Accumulators const.
template <int R>
__device__ __forceinline__ void emit_pixel(const float* sx, const float* sy,
                                           const float* sxx, const float* syy,
                                           const float* sxy,
                                           float* __restrict__ out,
                                           int b, int h, int w, int ri) {
  constexpr int K = 2 * R + 1;
  constexpr float inv_n = 1.0f / (K * K);
  float mx[6], my[6];
  #pragma unroll
  for (int c = 0; c < 6; ++c) { mx[c] = sx[c] * inv_n; my[c] = sy[c] * inv_n; }
  float cxy[36];
  #pragma unroll
  for (int i = 0; i < 6; ++i)
    #pragma unroll
    for (int j = 0; j < 6; ++j)
      cxy[i * 6 + j] = fmaf(-mx[i], my[j], sxy[i * 6 + j] * inv_n);
  float ax[21], ay[21];
  {
    int t = 0;
    #pragma unroll
    for (int i = 0; i < 6; ++i) {
      #pragma unroll
      for (int j = 0; j <= i; ++j) {
        const float e = (i == j) ? 1e-6f : 0.0f;
        ax[t] = sxx[t] * inv_n - mx[i] * mx[j] + e;
        ay[t] = syy[t] * inv_n - my[i] * my[j] + e;
        ++t;
      }
    }
  }
  cholinv6(ax);  // ax = Lx^{-1}
  cholinv6(ay);  // ay = Ly^{-1}
  float sim = 0.0f;
  #pragma unroll
  for (int i = 0; i < 6; ++i) {
    float di = 0.0f;
    #pragma unroll
    for (int j = 0; j <= i; ++j) {
      float inner = 0.0f;
      #pragma unroll
      for (int k = i; k < 6; ++k) inner += cxy[j * 6 + k] * ay[LT(k, i)];
      di += ax[LT(i, j)] * inner;
    }
    sim += fabsf(di);
  }
  out[((size_t)((b * 512 + h) * 512 + w)) * 2 + ri] = sim * (1.0f / 6.0f);
}

// Each thread owns a vertical strip of V output pixels in one column and
// slides the 90 window sums down: +entering row, -leaving row.
template <int R, int V>
__global__ __launch_bounds__(256, 2)
void cca_slide(const float* __restrict__ xg, const float* __restrict__ yg,
               float* __restrict__ out, const int ri) {
  constexpr int H = 512, W = 512, HW = H * W;
  constexpr int K = 2 * R + 1;

  const int b  = blockIdx.z;
  const int w0 = blockIdx.x * 16;
  const int h0 = blockIdx.y * (16 * V);
  const int tx = threadIdx.x & 15;
  const int g  = threadIdx.x >> 4;
  const int hbase = h0 + g * V;   // first output row of this thread's strip
  const int wc = w0 + tx;         // output column

  const float* xb = xg + (size_t)b * 6 * HW;
  const float* yb = yg + (size_t)b * 6 * HW;

  // Reflected column word-offsets for the K horizontal window positions.
  int cref[K];
  #pragma unroll
  for (int dx = 0; dx < K; ++dx) cref[dx] = reflect512(wc - R + dx);

  float sx[6] = {0, 0, 0, 0, 0, 0};
  float sy[6] = {0, 0, 0, 0, 0, 0};
  float sxx[21] = {0};
  float syy[21] = {0};
  float sxy[36] = {0};

  // Initial window for pixel (hbase, wc): rows hbase-R .. hbase+R.
  #pragma unroll 1
  for (int r = hbase - R; r <= hbase + R; ++r)
    row_acc<R, true>(xb, yb, reflect512(r) * W, cref, sx, sy, sxx, syy, sxy);

  emit_pixel<R>(sx, sy, sxx, syy, sxy, out, b, hbase, wc, ri);

  // Slide down V-1 times.
  #pragma unroll 1
  for (int s = 1; s < V; ++s) {
    row_acc<R, true >(xb, yb, reflect512(hbase + R + s) * W, cref,
                      sx, sy, sxx, syy, sxy);
    row_acc<R, false>(xb, yb, reflect512(hbase - R + s - 1) * W, cref,
                      sx, sy, sxx, syy, sxy);
    emit_pixel<R>(sx, sy, sxx, syy, sxy, out, b, hbase + s, wc, ri);
  }
}

extern "C" void kernel_launch(void* const* d_in, const int* in_sizes, int n_in,
                              void* d_out, int out_size, void* d_ws, size_t ws_size,
                              hipStream_t stream) {
  const float* x = (const float*)d_in[0];
  const float* y = (const float*)d_in[1];
  float* out = (float*)d_out;
  constexpr int V = 4;
  dim3 grid(512 / 16, 512 / (16 * V), 2);  // 32 x 8 x 2 = 512 blocks
  cca_slide<2, V><<<grid, dim3(256), 0, stream>>>(x, y, out, 0);
  cca_slide<4, V><<<grid, dim3(256), 0, stream>>>(x, y, out, 1);
}

// Round 3
// 242.487 us; speedup vs baseline: 1.6317x; 1.6317x over previous
//
#include <hip/hip_runtime.h>
#include <math.h>

// Lower-triangle flat index, j <= i
#define LT(i,j) ((i)*((i)+1)/2 + (j))

// reflect index into [0,512) for i in (-512, 1022)
__device__ __forceinline__ int reflect512(int i) {
  int a = (i < 0) ? -i : i;
  int b = 1022 - a;
  return (a < b) ? a : b;
}

// Packed-lower SPD 6x6 -> packed-lower L^{-1} in place. Divide/sqrt-free:
// v_rsq gives 1/L[j][j], which is also M[j][j] after inversion.
__device__ __forceinline__ void cholinv6(float* a) {
  #pragma unroll
  for (int j = 0; j < 6; ++j) {
    float d = a[LT(j,j)];
    #pragma unroll
    for (int p = 0; p < j; ++p) d -= a[LT(j,p)] * a[LT(j,p)];
    const float rd = __builtin_amdgcn_rsqf(d);   // 1/sqrt(d) = 1/L[j][j]
    a[LT(j,j)] = rd;
    #pragma unroll
    for (int i = j + 1; i < 6; ++i) {
      float s = a[LT(i,j)];
      #pragma unroll
      for (int p = 0; p < j; ++p) s -= a[LT(i,p)] * a[LT(j,p)];
      a[LT(i,j)] = s * rd;                       // L[i][j]
    }
  }
  // In-place lower-triangular inverse (column-major order is in-place safe).
  // a[LT(j,j)] already holds M[j][j] = 1/L[j][j].
  #pragma unroll
  for (int j = 0; j < 6; ++j) {
    #pragma unroll
    for (int i = j + 1; i < 6; ++i) {
      float s = 0.0f;
      #pragma unroll
      for (int p = j; p < i; ++p) s += a[LT(i,p)] * a[LT(p,j)];
      a[LT(i,j)] = -s * a[LT(i,i)];
    }
  }
}

template <int R>
__global__ __launch_bounds__(256, 2)
void cca_tile(const float* __restrict__ xg, const float* __restrict__ yg,
              float* __restrict__ out, const int ri) {
  constexpr int H = 512, W = 512, HW = H * W;
  constexpr int K = 2 * R + 1;
  constexpr int T = 16;           // 16x16 output tile
  constexpr int S = T + 2 * R;    // padded tile extent (24 or 20)
  constexpr int SP = 24;          // row stride: ty*24 mod 32 = {0,24,16,8} ->
                                  // uniform 2-way bank aliasing = free (m136).
                                  // (+1 pad stride 25 gave {0,25,18,11}: 3-4 way!)
  constexpr int CH = S * SP;      // channel stride (words)
  constexpr int YO = 6 * S * SP;  // y-plane offset (words)

  __shared__ float ls[2 * 6 * S * SP];

  const int b   = blockIdx.z;
  const int h0  = blockIdx.y * T;
  const int w0  = blockIdx.x * T;
  const int tid = threadIdx.x;

  // Stage reflect-padded x/y tiles. Single buffer => every window read below
  // is a ds_read with a compile-time immediate offset (max ~27.6 KB < 64 KB).
  for (int i = tid; i < 6 * S * S; i += 256) {
    const int c   = i / (S * S);
    const int rem = i - c * (S * S);
    const int row = rem / S;
    const int col = rem - row * S;
    const int h = reflect512(h0 - R + row);
    const int w = reflect512(w0 - R + col);
    const size_t gi = (size_t)(b * 6 + c) * HW + h * W + w;
    ls[c * CH + row * SP + col]      = xg[gi];
    ls[YO + c * CH + row * SP + col] = yg[gi];
  }
  __syncthreads();

  const int ty = tid >> 4;
  const int tx = tid & 15;
  const float* base = &ls[ty * SP + tx];

  float sx[6]   = {0, 0, 0, 0, 0, 0};
  float sy[6]   = {0, 0, 0, 0, 0, 0};
  float sxx[21] = {0};
  float syy[21] = {0};
  float sxy[36] = {0};

  #pragma unroll 1   // keep dy rolled: K*102-inst body already; avoid I$ blowout
  for (int dy = 0; dy < K; ++dy) {
    const float* rb = base + dy * SP;   // one v_add per row; reads below are imm-offset
    #pragma unroll
    for (int dx = 0; dx < K; ++dx) {
      float xv[6], yv[6];
      #pragma unroll
      for (int c = 0; c < 6; ++c) {
        xv[c] = rb[c * CH + dx];
        yv[c] = rb[YO + c * CH + dx];
      }
      #pragma unroll
      for (int c = 0; c < 6; ++c) { sx[c] += xv[c]; sy[c] += yv[c]; }
      int t = 0;
      #pragma unroll
      for (int i = 0; i < 6; ++i) {
        #pragma unroll
        for (int j = 0; j <= i; ++j) {
          sxx[t] += xv[i] * xv[j];
          syy[t] += yv[i] * yv[j];
          ++t;
        }
      }
      #pragma unroll
      for (int i = 0; i < 6; ++i)
        #pragma unroll
        for (int j = 0; j < 6; ++j) sxy[i * 6 + j] += xv[i] * yv[j];
    }
  }

  // Epilogue, fully in place on the accumulators (peak live ~= 102 + temps).
  constexpr float inv_n = 1.0f / (K * K);
  float mx[6], my[6];
  #pragma unroll
  for (int c = 0; c < 6; ++c) { mx[c] = sx[c] * inv_n; my[c] = sy[c] * inv_n; }
  {
    int t = 0;
    #pragma unroll
    for (int i = 0; i < 6; ++i) {
      #pragma unroll
      for (int j = 0; j <= i; ++j) {
        const float e = (i == j) ? 1e-6f : 0.0f;
        sxx[t] = sxx[t] * inv_n - mx[i] * mx[j] + e;
        syy[t] = syy[t] * inv_n - my[i] * my[j] + e;
        ++t;
      }
    }
  }
  #pragma unroll
  for (int i = 0; i < 6; ++i)
    #pragma unroll
    for (int j = 0; j < 6; ++j)
      sxy[i * 6 + j] = fmaf(-mx[i], my[j], sxy[i * 6 + j] * inv_n);

  cholinv6(sxx);  // sxx = Mx = Lx^{-1}
  cholinv6(syy);  // syy = My = Ly^{-1}

  // diag_i = sum_{j<=i} Mx[i][j] * ( sum_{k>=i} Cxy[j][k] * My[k][i] )
  float sim = 0.0f;
  #pragma unroll
  for (int i = 0; i < 6; ++i) {
    float di = 0.0f;
    #pragma unroll
    for (int j = 0; j <= i; ++j) {
      float inner = 0.0f;
      #pragma unroll
      for (int k = i; k < 6; ++k) inner += sxy[j * 6 + k] * syy[LT(k, i)];
      di += sxx[LT(i, j)] * inner;
    }
    sim += fabsf(di);
  }
  sim *= (1.0f / 6.0f);

  const int h = h0 + ty;
  const int w = w0 + tx;
  out[((size_t)((b * 512 + h) * 512 + w)) * 2 + ri] = sim;
}

extern "C" void kernel_launch(void* const* d_in, const int* in_sizes, int n_in,
                              void* d_out, int out_size, void* d_ws, size_t ws_size,
                              hipStream_t stream) {
  const float* x = (const float*)d_in[0];
  const float* y = (const float*)d_in[1];
  float* out = (float*)d_out;
  dim3 grid(512 / 16, 512 / 16, 2);  // (W tiles, H tiles, B)
  cca_tile<2><<<grid, dim3(256), 0, stream>>>(x, y, out, 0);
  cca_tile<4><<<grid, dim3(256), 0, stream>>>(x, y, out, 1);
}

// Round 4
// 194.339 us; speedup vs baseline: 2.0359x; 1.2478x over previous
//
#include <hip/hip_runtime.h>
#include <math.h>

typedef float v2f __attribute__((ext_vector_type(2)));
typedef float v4f __attribute__((ext_vector_type(4)));

// Lower-triangle flat index, j <= i
#define LT(i,j) ((i)*((i)+1)/2 + (j))

// reflect index into [0,512) for i in (-512, 1022)
__device__ __forceinline__ int reflect512(int i) {
  int a = (i < 0) ? -i : i;
  int b = 1022 - a;
  return (a < b) ? a : b;
}

// Gram entry g[a][b] (a>=b) from the 2x2-block pk accumulators.
// Block (Kp=a>>1, Pp=b>>1), t=LT(Kp,Pp):
//   accd[t] = (z[2Kp]*z[2Pp],   z[2Kp+1]*z[2Pp+1])   summed over window
//   accs[t] = (z[2Kp]*z[2Pp+1], z[2Kp+1]*z[2Pp])
// All a,b are compile-time after unrolling -> the branches fold away.
__device__ __forceinline__ float gget(const v2f* accd, const v2f* accs,
                                      int a, int b) {
  const int t = LT(a >> 1, b >> 1);
  if (((a & 1) == 0) && ((b & 1) == 0)) return accd[t].x;
  if (((a & 1) == 1) && ((b & 1) == 1)) return accd[t].y;
  if ((a & 1) == 0) return accs[t].x;
  return accs[t].y;
}

// Packed-lower SPD 6x6 -> packed-lower L^{-1} in place. Divide/sqrt-free.
__device__ __forceinline__ void cholinv6(float* a) {
  #pragma unroll
  for (int j = 0; j < 6; ++j) {
    float d = a[LT(j,j)];
    #pragma unroll
    for (int p = 0; p < j; ++p) d -= a[LT(j,p)] * a[LT(j,p)];
    const float rd = __builtin_amdgcn_rsqf(d);   // 1/sqrt(d) = 1/L[j][j]
    a[LT(j,j)] = rd;
    #pragma unroll
    for (int i = j + 1; i < 6; ++i) {
      float s = a[LT(i,j)];
      #pragma unroll
      for (int p = 0; p < j; ++p) s -= a[LT(i,p)] * a[LT(j,p)];
      a[LT(i,j)] = s * rd;
    }
  }
  #pragma unroll
  for (int j = 0; j < 6; ++j) {
    #pragma unroll
    for (int i = j + 1; i < 6; ++i) {
      float s = 0.0f;
      #pragma unroll
      for (int p = j; p < i; ++p) s += a[LT(i,p)] * a[LT(p,j)];
      a[LT(i,j)] = -s * a[LT(i,i)];
    }
  }
}

template <int R>
__global__ __launch_bounds__(256, 3)
void cca_pk(const float* __restrict__ xg, const float* __restrict__ yg,
            float* __restrict__ out, const int ri) {
  constexpr int H = 512, W = 512, HW = H * W;
  constexpr int K = 2 * R + 1;
  constexpr int T = 16;          // 16x16 output tile
  constexpr int S = T + 2 * R;   // padded extent (24 / 20)

  // Channel-interleaved LDS: 12 floats [x0..x5,y0..y5] per pixel.
  // Pixel stride 12 words = 48 B -> every v4f slot is 16B-aligned.
  __shared__ __align__(16) float ls[S * S * 12];

  const int b   = blockIdx.z;
  const int h0  = blockIdx.y * T;
  const int w0  = blockIdx.x * T;
  const int tid = threadIdx.x;

  // Stage: coalesced per-plane global reads, 3x ds_write_b128 per pixel.
  for (int i = tid; i < S * S; i += 256) {
    const int row = i / S;
    const int col = i - row * S;
    const int h = reflect512(h0 - R + row);
    const int w = reflect512(w0 - R + col);
    const size_t gp = (size_t)b * 6 * HW + (size_t)h * W + w;
    float xv[6], yv[6];
    #pragma unroll
    for (int c = 0; c < 6; ++c) {
      xv[c] = xg[gp + c * HW];
      yv[c] = yg[gp + c * HW];
    }
    v4f w0v = {xv[0], xv[1], xv[2], xv[3]};
    v4f w1v = {xv[4], xv[5], yv[0], yv[1]};
    v4f w2v = {yv[2], yv[3], yv[4], yv[5]};
    *(v4f*)&ls[i * 12 + 0] = w0v;
    *(v4f*)&ls[i * 12 + 4] = w1v;
    *(v4f*)&ls[i * 12 + 8] = w2v;
  }
  __syncthreads();

  const int ty = tid >> 4;
  const int tx = tid & 15;

  v2f zs[6]   = {};   // pair sums: (x0,x1)(x2,x3)(x4,x5)(y0,y1)(y2,y3)(y4,y5)
  v2f accd[21] = {};  // 2x2 Gram blocks, direct lanes
  v2f accs[21] = {};  // 2x2 Gram blocks, swapped lanes

  #pragma unroll 1   // keep dy rolled: dx body is ~500 inst
  for (int dy = 0; dy < K; ++dy) {
    const int rowbase = ((ty + dy) * S + tx) * 12;
    #pragma unroll
    for (int dx = 0; dx < K; ++dx) {
      const v4f l0 = *(const v4f*)&ls[rowbase + dx * 12 + 0];
      const v4f l1 = *(const v4f*)&ls[rowbase + dx * 12 + 4];
      const v4f l2 = *(const v4f*)&ls[rowbase + dx * 12 + 8];
      v2f z[6];
      z[0] = l0.lo; z[1] = l0.hi;
      z[2] = l1.lo; z[3] = l1.hi;
      z[4] = l2.lo; z[5] = l2.hi;
      #pragma unroll
      for (int p = 0; p < 6; ++p) zs[p] += z[p];
      int t = 0;
      #pragma unroll
      for (int Kp = 0; Kp < 6; ++Kp) {
        #pragma unroll
        for (int Pp = 0; Pp <= Kp; ++Pp) {
          const v2f c  = z[Pp];
          const v2f cs = __builtin_shufflevector(c, c, 1, 0);  // op_sel fold
          accd[t] = __builtin_elementwise_fma(z[Kp], c,  accd[t]);
          accs[t] = __builtin_elementwise_fma(z[Kp], cs, accs[t]);
          ++t;
        }
      }
    }
  }

  // ---- Epilogue (materialize covariances incrementally to cap pressure) ----
  constexpr float inv_n = 1.0f / (K * K);
  float mx[6], my[6];
  #pragma unroll
  for (int i = 0; i < 6; ++i) {
    mx[i] = ((i & 1) ? zs[i >> 1].y : zs[i >> 1].x) * inv_n;
    my[i] = ((i & 1) ? zs[3 + (i >> 1)].y : zs[3 + (i >> 1)].x) * inv_n;
  }

  float ax[21];
  {
    int t = 0;
    #pragma unroll
    for (int i = 0; i < 6; ++i)
      #pragma unroll
      for (int j = 0; j <= i; ++j) {
        const float e = (i == j) ? 1e-6f : 0.0f;
        ax[t] = gget(accd, accs, i, j) * inv_n - mx[i] * mx[j] + e;
        ++t;
      }
  }
  cholinv6(ax);  // ax = Lx^{-1}

  float ay[21];
  {
    int t = 0;
    #pragma unroll
    for (int i = 0; i < 6; ++i)
      #pragma unroll
      for (int j = 0; j <= i; ++j) {
        const float e = (i == j) ? 1e-6f : 0.0f;
        ay[t] = gget(accd, accs, 6 + i, 6 + j) * inv_n - my[i] * my[j] + e;
        ++t;
      }
  }
  cholinv6(ay);  // ay = Ly^{-1}

  float cxy[36];
  #pragma unroll
  for (int i = 0; i < 6; ++i)
    #pragma unroll
    for (int j = 0; j < 6; ++j)
      // sxy[i][j] = sum x_i y_j = Gram[6+j][i] (lower block)
      cxy[i * 6 + j] = fmaf(-mx[i], my[j], gget(accd, accs, 6 + j, i) * inv_n);

  // diag_i = sum_{j<=i} Mx[i][j] * ( sum_{k>=i} Cxy[j][k] * My[k][i] )
  float sim = 0.0f;
  #pragma unroll
  for (int i = 0; i < 6; ++i) {
    float di = 0.0f;
    #pragma unroll
    for (int j = 0; j <= i; ++j) {
      float inner = 0.0f;
      #pragma unroll
      for (int k = i; k < 6; ++k) inner += cxy[j * 6 + k] * ay[LT(k, i)];
      di += ax[LT(i, j)] * inner;
    }
    sim += fabsf(di);
  }
  sim *= (1.0f / 6.0f);

  const int h = h0 + ty;
  const int w = w0 + tx;
  out[((size_t)((b * 512 + h) * 512 + w)) * 2 + ri] = sim;
}

extern "C" void kernel_launch(void* const* d_in, const int* in_sizes, int n_in,
                              void* d_out, int out_size, void* d_ws, size_t ws_size,
                              hipStream_t stream) {
  const float* x = (const float*)d_in[0];
  const float* y = (const float*)d_in[1];
  float* out = (float*)d_out;
  dim3 grid(512 / 16, 512 / 16, 2);  // (W tiles, H tiles, B)
  cca_pk<2><<<grid, dim3(256), 0, stream>>>(x, y, out, 0);
  cca_pk<4><<<grid, dim3(256), 0, stream>>>(x, y, out, 1);
}

// Round 5
// 151.440 us; speedup vs baseline: 2.6127x; 1.2833x over previous
//
#include <hip/hip_runtime.h>
#include <math.h>

typedef float v2f __attribute__((ext_vector_type(2)));
typedef float v4f __attribute__((ext_vector_type(4)));

// Lower-triangle flat index, j <= i
#define LT(i,j) ((i)*((i)+1)/2 + (j))

// reflect index into [0,512) for i in (-512, 1022)
__device__ __forceinline__ int reflect512(int i) {
  int a = (i < 0) ? -i : i;
  int b = 1022 - a;
  return (a < b) ? a : b;
}

// Gram entry g[a][b] (a>=b) from the 2x2-block pk accumulators.
// Block (Kp=a>>1, Pp=b>>1), t=LT(Kp,Pp):
//   accd[t] = (z[2Kp]*z[2Pp],   z[2Kp+1]*z[2Pp+1])   summed over window
//   accs[t] = (z[2Kp]*z[2Pp+1], z[2Kp+1]*z[2Pp])
__device__ __forceinline__ float gget(const v2f* accd, const v2f* accs,
                                      int a, int b) {
  const int t = LT(a >> 1, b >> 1);
  if (((a & 1) == 0) && ((b & 1) == 0)) return accd[t].x;
  if (((a & 1) == 1) && ((b & 1) == 1)) return accd[t].y;
  if ((a & 1) == 0) return accs[t].x;
  return accs[t].y;
}

// Packed-lower SPD 6x6 -> packed-lower L^{-1} in place. Divide/sqrt-free.
__device__ __forceinline__ void cholinv6(float* a) {
  #pragma unroll
  for (int j = 0; j < 6; ++j) {
    float d = a[LT(j,j)];
    #pragma unroll
    for (int p = 0; p < j; ++p) d -= a[LT(j,p)] * a[LT(j,p)];
    const float rd = __builtin_amdgcn_rsqf(d);   // 1/sqrt(d) = 1/L[j][j]
    a[LT(j,j)] = rd;
    #pragma unroll
    for (int i = j + 1; i < 6; ++i) {
      float s = a[LT(i,j)];
      #pragma unroll
      for (int p = 0; p < j; ++p) s -= a[LT(i,p)] * a[LT(j,p)];
      a[LT(i,j)] = s * rd;
    }
  }
  #pragma unroll
  for (int j = 0; j < 6; ++j) {
    #pragma unroll
    for (int i = j + 1; i < 6; ++i) {
      float s = 0.0f;
      #pragma unroll
      for (int p = j; p < i; ++p) s += a[LT(i,p)] * a[LT(p,j)];
      a[LT(i,j)] = -s * a[LT(i,i)];
    }
  }
}

// +/- one padded row's K window positions into the pk Gram accumulators.
// SW = padded row width (pixels), ls entries are 12-float interleaved pixels.
template <int K, bool ADD>
__device__ __forceinline__ void row_acc_pk(const float* __restrict__ ls,
                                           int rowbase,
                                           v2f* zs, v2f* accd, v2f* accs) {
  #pragma unroll
  for (int dx = 0; dx < K; ++dx) {
    const v4f l0 = *(const v4f*)&ls[rowbase + dx * 12 + 0];
    const v4f l1 = *(const v4f*)&ls[rowbase + dx * 12 + 4];
    const v4f l2 = *(const v4f*)&ls[rowbase + dx * 12 + 8];
    v2f z[6];
    z[0] = l0.lo; z[1] = l0.hi;
    z[2] = l1.lo; z[3] = l1.hi;
    z[4] = l2.lo; z[5] = l2.hi;
    #pragma unroll
    for (int p = 0; p < 6; ++p) zs[p] = ADD ? (zs[p] + z[p]) : (zs[p] - z[p]);
    int t = 0;
    #pragma unroll
    for (int Kp = 0; Kp < 6; ++Kp) {
      #pragma unroll
      for (int Pp = 0; Pp <= Kp; ++Pp) {
        const v2f c  = z[Pp];
        const v2f cs = __builtin_shufflevector(c, c, 1, 0);  // op_sel fold
        const v2f a  = ADD ? z[Kp] : -z[Kp];
        accd[t] = __builtin_elementwise_fma(a, c,  accd[t]);
        accs[t] = __builtin_elementwise_fma(a, cs, accs[t]);
        ++t;
      }
    }
  }
}

// Covariances -> Cholesky-inverse -> mean |diag|. Accumulators stay live.
template <int K>
__device__ __forceinline__ float emit_sim(const v2f* zs, const v2f* accd,
                                          const v2f* accs) {
  constexpr float inv_n = 1.0f / (K * K);
  float mx[6], my[6];
  #pragma unroll
  for (int i = 0; i < 6; ++i) {
    mx[i] = ((i & 1) ? zs[i >> 1].y : zs[i >> 1].x) * inv_n;
    my[i] = ((i & 1) ? zs[3 + (i >> 1)].y : zs[3 + (i >> 1)].x) * inv_n;
  }
  float ax[21];
  {
    int t = 0;
    #pragma unroll
    for (int i = 0; i < 6; ++i)
      #pragma unroll
      for (int j = 0; j <= i; ++j) {
        const float e = (i == j) ? 1e-6f : 0.0f;
        ax[t] = gget(accd, accs, i, j) * inv_n - mx[i] * mx[j] + e;
        ++t;
      }
  }
  cholinv6(ax);  // ax = Lx^{-1}
  float ay[21];
  {
    int t = 0;
    #pragma unroll
    for (int i = 0; i < 6; ++i)
      #pragma unroll
      for (int j = 0; j <= i; ++j) {
        const float e = (i == j) ? 1e-6f : 0.0f;
        ay[t] = gget(accd, accs, 6 + i, 6 + j) * inv_n - my[i] * my[j] + e;
        ++t;
      }
  }
  cholinv6(ay);  // ay = Ly^{-1}
  float cxy[36];
  #pragma unroll
  for (int i = 0; i < 6; ++i)
    #pragma unroll
    for (int j = 0; j < 6; ++j)
      // sxy[i][j] = sum x_i y_j = Gram[6+j][i] (lower block)
      cxy[i * 6 + j] = fmaf(-mx[i], my[j], gget(accd, accs, 6 + j, i) * inv_n);
  float sim = 0.0f;
  #pragma unroll
  for (int i = 0; i < 6; ++i) {
    float di = 0.0f;
    #pragma unroll
    for (int j = 0; j <= i; ++j) {
      float inner = 0.0f;
      #pragma unroll
      for (int k = i; k < 6; ++k) inner += cxy[j * 6 + k] * ay[LT(k, i)];
      di += ax[LT(i, j)] * inner;
    }
    sim += fabsf(di);
  }
  return sim * (1.0f / 6.0f);
}

// 16 tx x 16 strips, each strip = V vertically-adjacent outputs computed by
// sliding the window: K^2 initial positions, then +K / -K per step.
template <int R, int V>
__global__ __launch_bounds__(256, 2)
void cca_slide_pk(const float* __restrict__ xg, const float* __restrict__ yg,
                  float* __restrict__ out, const int ri) {
  constexpr int H = 512, W = 512, HW = H * W;
  constexpr int K = 2 * R + 1;
  constexpr int TW = 16;            // tile width
  constexpr int TH = 16 * V;        // tile height (32)
  constexpr int SW = TW + 2 * R;    // padded width  (24 / 20)
  constexpr int SH = TH + 2 * R;    // padded height (40 / 36)

  // Channel-interleaved pixels: 12 floats [x0..x5,y0..y5], 48 B stride.
  __shared__ __align__(16) float ls[SH * SW * 12];   // r4: 46 KB, r2: 34.5 KB

  const int b   = blockIdx.z;
  const int h0  = blockIdx.y * TH;
  const int w0  = blockIdx.x * TW;
  const int tid = threadIdx.x;

  for (int i = tid; i < SH * SW; i += 256) {
    const int row = i / SW;
    const int col = i - row * SW;
    const int h = reflect512(h0 - R + row);
    const int w = reflect512(w0 - R + col);
    const size_t gp = (size_t)b * 6 * HW + (size_t)h * W + w;
    float xv[6], yv[6];
    #pragma unroll
    for (int c = 0; c < 6; ++c) {
      xv[c] = xg[gp + c * HW];
      yv[c] = yg[gp + c * HW];
    }
    v4f p0 = {xv[0], xv[1], xv[2], xv[3]};
    v4f p1 = {xv[4], xv[5], yv[0], yv[1]};
    v4f p2 = {yv[2], yv[3], yv[4], yv[5]};
    *(v4f*)&ls[i * 12 + 0] = p0;
    *(v4f*)&ls[i * 12 + 4] = p1;
    *(v4f*)&ls[i * 12 + 8] = p2;
  }
  __syncthreads();

  const int tx = tid & 15;
  const int g  = tid >> 4;
  const int r0 = g * V;            // first output row (tile-local)

  v2f zs[6]    = {};
  v2f accd[21] = {};
  v2f accs[21] = {};

  // Initial window: padded rows r0 .. r0+2R.
  #pragma unroll 1
  for (int dy = 0; dy < K; ++dy)
    row_acc_pk<K, true>(ls, ((r0 + dy) * SW + tx) * 12, zs, accd, accs);

  out[((size_t)((b * H + h0 + r0) * W + w0 + tx)) * 2 + ri] =
      emit_sim<K>(zs, accd, accs);

  #pragma unroll 1
  for (int s = 1; s < V; ++s) {
    row_acc_pk<K, true >(ls, ((r0 + s + 2 * R) * SW + tx) * 12, zs, accd, accs);
    row_acc_pk<K, false>(ls, ((r0 + s - 1)     * SW + tx) * 12, zs, accd, accs);
    out[((size_t)((b * H + h0 + r0 + s) * W + w0 + tx)) * 2 + ri] =
        emit_sim<K>(zs, accd, accs);
  }
}

extern "C" void kernel_launch(void* const* d_in, const int* in_sizes, int n_in,
                              void* d_out, int out_size, void* d_ws, size_t ws_size,
                              hipStream_t stream) {
  const float* x = (const float*)d_in[0];
  const float* y = (const float*)d_in[1];
  float* out = (float*)d_out;
  constexpr int V = 2;
  dim3 grid(512 / 16, 512 / (16 * V), 2);   // 32 x 16 x 2 = 1024 blocks
  cca_slide_pk<2, V><<<grid, dim3(256), 0, stream>>>(x, y, out, 0);
  cca_slide_pk<4, V><<<grid, dim3(256), 0, stream>>>(x, y, out, 1);
}

// Round 7
// 145.457 us; speedup vs baseline: 2.7201x; 1.0411x over previous
//
#include <hip/hip_runtime.h>
#include <math.h>

typedef unsigned int u32;
typedef _Float16 f16x2 __attribute__((ext_vector_type(2)));

// Lower-triangle flat index, j <= i (used up to 12x12 -> 78 entries)
#define LT(i,j) ((i)*((i)+1)/2 + (j))

union HU { u32 u; f16x2 h; };
static __device__ __forceinline__ f16x2 asH(u32 u) { HU x; x.u = u; return x.h; }
static __device__ __forceinline__ u32 asU(f16x2 h) { HU x; x.h = h; return x.u; }

// __builtin_amdgcn_cvt_pkrtz returns __fp16x2 (not _Float16x2); bit-cast it.
static __device__ __forceinline__ u32 pkrtz(float a, float b) {
  union { decltype(__builtin_amdgcn_cvt_pkrtz(0.f, 0.f)) h; u32 u; } x;
  x.h = __builtin_amdgcn_cvt_pkrtz(a, b);
  return x.u;
}

static __device__ __forceinline__ float fdot2(f16x2 a, f16x2 b, float c) {
  return __builtin_amdgcn_fdot2(a, b, c, false);  // c + a.x*b.x + a.y*b.y (f32 acc)
}

// reflect index into [0,512)
__device__ __forceinline__ int reflect512(int i) {
  int a = (i < 0) ? -i : i;
  int b = 1022 - a;
  return (a < b) ? a : b;
}

__device__ __forceinline__ void load12(const u32* cell, u32* hu) {
  const uint4 q0 = *(const uint4*)(cell + 0);
  const uint4 q1 = *(const uint4*)(cell + 4);
  const uint4 q2 = *(const uint4*)(cell + 8);
  hu[0] = q0.x; hu[1] = q0.y; hu[2]  = q0.z; hu[3]  = q0.w;
  hu[4] = q1.x; hu[5] = q1.y; hu[6]  = q1.z; hu[7]  = q1.w;
  hu[8] = q2.x; hu[9] = q2.y; hu[10] = q2.z; hu[11] = q2.w;
}

// Full pair-row position: both rows of the pair are in the window.
__device__ __forceinline__ void pair_pass(const u32* cell, float* acc, float* sums) {
  u32 hu[12];
  load12(cell, hu);
  const f16x2 one2 = {(_Float16)1.0f, (_Float16)1.0f};
  #pragma unroll
  for (int a = 0; a < 12; ++a) sums[a] = fdot2(asH(hu[a]), one2, sums[a]);
  #pragma unroll
  for (int a = 0; a < 12; ++a)
    #pragma unroll
    for (int b = 0; b <= a; ++b)
      acc[LT(a, b)] = fdot2(asH(hu[a]), asH(hu[b]), acc[LT(a, b)]);
}

// Only the EVEN row (elem0) of the pair is in the window: mask elem1 to 0
// on one operand (x*0 == 0 for finite data).
__device__ __forceinline__ void single_pass(const u32* cell, float* acc, float* sums) {
  u32 hu[12], hm[12];
  load12(cell, hu);
  #pragma unroll
  for (int b = 0; b < 12; ++b) hm[b] = hu[b] & 0x0000FFFFu;
  const f16x2 c10 = {(_Float16)1.0f, (_Float16)0.0f};
  #pragma unroll
  for (int a = 0; a < 12; ++a) sums[a] = fdot2(asH(hu[a]), c10, sums[a]);
  #pragma unroll
  for (int a = 0; a < 12; ++a)
    #pragma unroll
    for (int b = 0; b <= a; ++b)
      acc[LT(a, b)] = fdot2(asH(hu[a]), asH(hm[b]), acc[LT(a, b)]);
}

// Fused slide: window += row(new) - row(old). old = elem0 of pair p0,
// new = elem1 of pair p1. A = (z_old, z_new) via v_perm; B = A with elem0
// sign-flipped -> fdot2(A,B) = -z_old[a]z_old[b] + z_new[a]z_new[b].
__device__ __forceinline__ void delta_pass(const u32* p0, const u32* p1,
                                           float* acc, float* sums) {
  u32 u0[12], u1[12], A[12], B[12];
  load12(p0, u0);
  load12(p1, u1);
  #pragma unroll
  for (int ch = 0; ch < 12; ++ch) {
    A[ch] = __builtin_amdgcn_perm(u1[ch], u0[ch], 0x07060100u);  // (u0.lo16, u1.hi16)
    B[ch] = A[ch] ^ 0x00008000u;                                  // negate elem0
  }
  const f16x2 mneg = {(_Float16)-1.0f, (_Float16)1.0f};
  #pragma unroll
  for (int a = 0; a < 12; ++a) sums[a] = fdot2(asH(A[a]), mneg, sums[a]);
  #pragma unroll
  for (int a = 0; a < 12; ++a)
    #pragma unroll
    for (int b = 0; b <= a; ++b)
      acc[LT(a, b)] = fdot2(asH(A[a]), asH(B[b]), acc[LT(a, b)]);
}

// Packed-lower SPD 6x6 -> packed-lower L^{-1} in place. Divide/sqrt-free.
__device__ __forceinline__ void cholinv6(float* a) {
  #pragma unroll
  for (int j = 0; j < 6; ++j) {
    float d = a[LT(j,j)];
    #pragma unroll
    for (int p = 0; p < j; ++p) d -= a[LT(j,p)] * a[LT(j,p)];
    const float rd = __builtin_amdgcn_rsqf(d);
    a[LT(j,j)] = rd;
    #pragma unroll
    for (int i = j + 1; i < 6; ++i) {
      float s = a[LT(i,j)];
      #pragma unroll
      for (int p = 0; p < j; ++p) s -= a[LT(i,p)] * a[LT(j,p)];
      a[LT(i,j)] = s * rd;
    }
  }
  #pragma unroll
  for (int j = 0; j < 6; ++j) {
    #pragma unroll
    for (int i = j + 1; i < 6; ++i) {
      float s = 0.0f;
      #pragma unroll
      for (int p = j; p < i; ++p) s += a[LT(i,p)] * a[LT(p,j)];
      a[LT(i,j)] = -s * a[LT(i,i)];
    }
  }
}

__device__ __forceinline__ float gg(const float* acc, int a, int b) {
  return (a >= b) ? acc[LT(a, b)] : acc[LT(b, a)];
}

template <int K>
__device__ __forceinline__ float emit_sim(const float* acc, const float* sums) {
  constexpr float inv_n = 1.0f / (K * K);
  float mx[6], my[6];
  #pragma unroll
  for (int i = 0; i < 6; ++i) {
    mx[i] = sums[i] * inv_n;
    my[i] = sums[6 + i] * inv_n;
  }
  float ax[21];
  {
    int t = 0;
    #pragma unroll
    for (int i = 0; i < 6; ++i)
      #pragma unroll
      for (int j = 0; j <= i; ++j) {
        const float e = (i == j) ? 1e-6f : 0.0f;
        ax[t] = gg(acc, i, j) * inv_n - mx[i] * mx[j] + e;
        ++t;
      }
  }
  cholinv6(ax);  // ax = Lx^{-1}
  float ay[21];
  {
    int t = 0;
    #pragma unroll
    for (int i = 0; i < 6; ++i)
      #pragma unroll
      for (int j = 0; j <= i; ++j) {
        const float e = (i == j) ? 1e-6f : 0.0f;
        ay[t] = gg(acc, 6 + i, 6 + j) * inv_n - my[i] * my[j] + e;
        ++t;
      }
  }
  cholinv6(ay);  // ay = Ly^{-1}
  float cxy[36];
  #pragma unroll
  for (int i = 0; i < 6; ++i)
    #pragma unroll
    for (int j = 0; j < 6; ++j)
      // sxy[i][j] = sum x_i y_j = Gram[6+j][i]
      cxy[i * 6 + j] = fmaf(-mx[i], my[j], acc[LT(6 + j, i)] * inv_n);
  float sim = 0.0f;
  #pragma unroll
  for (int i = 0; i < 6; ++i) {
    float di = 0.0f;
    #pragma unroll
    for (int j = 0; j <= i; ++j) {
      float inner = 0.0f;
      #pragma unroll
      for (int k = i; k < 6; ++k) inner += cxy[j * 6 + k] * ay[LT(k, i)];
      di += ax[LT(i, j)] * inner;
    }
    sim += fabsf(di);
  }
  return sim * (1.0f / 6.0f);
}

// One radius, one batch. 16 tx x 16 strips, V=2 outputs per strip (rows 2g,
// 2g+1): even strip starts keep all vertical pairs aligned.
template <int R>
__device__ __forceinline__ void run(const float* __restrict__ xg,
                                    const float* __restrict__ yg,
                                    float* __restrict__ out,
                                    int b, int ri, u32* lsu) {
  constexpr int K = 2 * R + 1;
  constexpr int H = 512, W = 512, HW = H * W;
  constexpr int TW = 16, TH = 32;
  constexpr int SW = TW + 2 * R;   // 24 / 20
  constexpr int SH = TH + 2 * R;   // 40 / 36 (even)
  constexpr int PR = SH / 2;       // pair rows

  const int h0  = blockIdx.y * TH;
  const int w0  = blockIdx.x * TW;
  const int tid = threadIdx.x;

  // Stage f16 pair-interleaved: cell (pr,c) holds 12 half2 = (row 2pr, row 2pr+1).
  for (int i = tid; i < PR * SW; i += 256) {
    const int pr = i / SW;
    const int c  = i - pr * SW;
    const int hA = reflect512(h0 - R + 2 * pr);
    const int hB = reflect512(h0 - R + 2 * pr + 1);
    const int w  = reflect512(w0 - R + c);
    const size_t gA = (size_t)b * 6 * HW + (size_t)hA * W + w;
    const size_t gB = (size_t)b * 6 * HW + (size_t)hB * W + w;
    #pragma unroll
    for (int ch = 0; ch < 6; ++ch) {
      lsu[i * 12 + ch]     = pkrtz(xg[gA + ch * HW], xg[gB + ch * HW]);
      lsu[i * 12 + 6 + ch] = pkrtz(yg[gA + ch * HW], yg[gB + ch * HW]);
    }
  }
  __syncthreads();

  const int tx = tid & 15;
  const int g  = tid >> 4;          // strip; output rows 2g, 2g+1 (tile-local)

  float acc[78]  = {};   // 12x12 Gram lower triangle (f32, fdot2-accumulated)
  float sums[12] = {};

  const u32* base = lsu + (g * SW + tx) * 12;

  // Window1 rows [2g, 2g+2R]: K/2 full pairs + single even row of pair g+K/2.
  #pragma unroll 1
  for (int i = 0; i < K / 2; ++i) {
    const u32* p = base + i * SW * 12;
    #pragma unroll 1
    for (int dx = 0; dx < K; ++dx) { pair_pass(p, acc, sums); p += 12; }
  }
  {
    const u32* p = base + (K / 2) * SW * 12;
    #pragma unroll 1
    for (int dx = 0; dx < K; ++dx) { single_pass(p, acc, sums); p += 12; }
  }
  out[((size_t)((b * H + h0 + 2 * g) * W + w0 + tx)) * 2 + ri] =
      emit_sim<K>(acc, sums);

  // Window2 = Window1 + row(2g+K) - row(2g): fused +/- pass.
  {
    const u32* p0 = base;                       // pair g   (old = elem0)
    const u32* p1 = base + (K / 2) * SW * 12;   // pair g+K/2 (new = elem1)
    #pragma unroll 1
    for (int dx = 0; dx < K; ++dx) { delta_pass(p0, p1, acc, sums); p0 += 12; p1 += 12; }
  }
  out[((size_t)((b * H + h0 + 2 * g + 1) * W + w0 + tx)) * 2 + ri] =
      emit_sim<K>(acc, sums);
}

// Merged dispatch: z in {0,1} -> r=2 batch z; z in {2,3} -> r=4 batch z-2.
__global__ __launch_bounds__(256, 2)
void cca_dot2(const float* __restrict__ xg, const float* __restrict__ yg,
              float* __restrict__ out) {
  __shared__ u32 lsu[20 * 24 * 12];   // 23 KB, sized for r=4
  const int z = blockIdx.z;
  if (z < 2) run<2>(xg, yg, out, z, 0, lsu);
  else       run<4>(xg, yg, out, z - 2, 1, lsu);
}

extern "C" void kernel_launch(void* const* d_in, const int* in_sizes, int n_in,
                              void* d_out, int out_size, void* d_ws, size_t ws_size,
                              hipStream_t stream) {
  const float* x = (const float*)d_in[0];
  const float* y = (const float*)d_in[1];
  float* out = (float*)d_out;
  dim3 grid(512 / 16, 512 / 32, 4);   // 32 x 16 x 4
  cca_dot2<<<grid, dim3(256), 0, stream>>>(x, y, out);
}

// Round 8
// 137.231 us; speedup vs baseline: 2.8832x; 1.0599x over previous
//
#include <hip/hip_runtime.h>
#include <math.h>

typedef float v2f __attribute__((ext_vector_type(2)));
typedef float v4f __attribute__((ext_vector_type(4)));

#define LT(i,j) ((i)*((i)+1)/2 + (j))

// reflect index into [0,512)
__device__ __forceinline__ int reflect512(int i) {
  int a = (i < 0) ? -i : i;
  int b = 1022 - a;
  return (a < b) ? a : b;
}

// ---- halo'd interleaved buffer: zb[b][520][520][12] f32, halo=4, reflected.
// pixel layout: [x0x1][x2x3][x4x5][y0y1][y2y3][y4y5] (3 x 16B)
constexpr int HB  = 520;          // 512 + 2*4 halo
constexpr int PS  = 12;           // words per pixel
constexpr int RS  = HB * PS;      // words per halo row (6240)

__global__ __launch_bounds__(256)
void prep_interleave(const float* __restrict__ xg, const float* __restrict__ yg,
                     float* __restrict__ zb) {
  constexpr int H = 512, W = 512, HW = H * W;
  const int idx = blockIdx.x * 256 + threadIdx.x;
  if (idx >= 2 * HB * HB) return;
  const int b  = idx / (HB * HB);
  const int r2 = idx - b * (HB * HB);
  const int hr = r2 / HB;
  const int wc = r2 - hr * HB;
  const int h = reflect512(hr - 4);
  const int w = reflect512(wc - 4);
  const size_t gp = (size_t)b * 6 * HW + (size_t)h * W + w;
  float xv[6], yv[6];
  #pragma unroll
  for (int c = 0; c < 6; ++c) {
    xv[c] = xg[gp + c * HW];
    yv[c] = yg[gp + c * HW];
  }
  float* o = zb + (size_t)idx * PS;
  v4f p0 = {xv[0], xv[1], xv[2], xv[3]};
  v4f p1 = {xv[4], xv[5], yv[0], yv[1]};
  v4f p2 = {yv[2], yv[3], yv[4], yv[5]};
  *(v4f*)(o + 0) = p0;
  *(v4f*)(o + 4) = p1;
  *(v4f*)(o + 8) = p2;
}

// Gram entry g[a][b] (a>=b) from the 2x2-block pk accumulators.
__device__ __forceinline__ float gget(const v2f* accd, const v2f* accs,
                                      int a, int b) {
  const int t = LT(a >> 1, b >> 1);
  if (((a & 1) == 0) && ((b & 1) == 0)) return accd[t].x;
  if (((a & 1) == 1) && ((b & 1) == 1)) return accd[t].y;
  if ((a & 1) == 0) return accs[t].x;
  return accs[t].y;
}

// Packed-lower SPD 6x6 -> packed-lower L^{-1} in place. Divide/sqrt-free.
__device__ __forceinline__ void cholinv6(float* a) {
  #pragma unroll
  for (int j = 0; j < 6; ++j) {
    float d = a[LT(j,j)];
    #pragma unroll
    for (int p = 0; p < j; ++p) d -= a[LT(j,p)] * a[LT(j,p)];
    const float rd = __builtin_amdgcn_rsqf(d);
    a[LT(j,j)] = rd;
    #pragma unroll
    for (int i = j + 1; i < 6; ++i) {
      float s = a[LT(i,j)];
      #pragma unroll
      for (int p = 0; p < j; ++p) s -= a[LT(i,p)] * a[LT(j,p)];
      a[LT(i,j)] = s * rd;
    }
  }
  #pragma unroll
  for (int j = 0; j < 6; ++j) {
    #pragma unroll
    for (int i = j + 1; i < 6; ++i) {
      float s = 0.0f;
      #pragma unroll
      for (int p = j; p < i; ++p) s += a[LT(i,p)] * a[LT(p,j)];
      a[LT(i,j)] = -s * a[LT(i,i)];
    }
  }
}

// +/- one window row's K pixels into the pk Gram accumulators; p points at
// the row's first (leftmost) pixel. All loads are dwordx4 w/ imm offsets.
template <int K, bool ADD>
__device__ __forceinline__ void row_acc_g(const float* __restrict__ p,
                                          v2f* zs, v2f* accd, v2f* accs) {
  #pragma unroll
  for (int dx = 0; dx < K; ++dx) {
    const v4f l0 = *(const v4f*)(p + dx * PS + 0);
    const v4f l1 = *(const v4f*)(p + dx * PS + 4);
    const v4f l2 = *(const v4f*)(p + dx * PS + 8);
    v2f z[6];
    z[0] = l0.lo; z[1] = l0.hi;
    z[2] = l1.lo; z[3] = l1.hi;
    z[4] = l2.lo; z[5] = l2.hi;
    #pragma unroll
    for (int q = 0; q < 6; ++q) zs[q] = ADD ? (zs[q] + z[q]) : (zs[q] - z[q]);
    int t = 0;
    #pragma unroll
    for (int Kp = 0; Kp < 6; ++Kp) {
      #pragma unroll
      for (int Pp = 0; Pp <= Kp; ++Pp) {
        const v2f c  = z[Pp];
        const v2f cs = __builtin_shufflevector(c, c, 1, 0);
        const v2f a  = ADD ? z[Kp] : -z[Kp];
        accd[t] = __builtin_elementwise_fma(a, c,  accd[t]);
        accs[t] = __builtin_elementwise_fma(a, cs, accs[t]);
        ++t;
      }
    }
  }
}

template <int K>
__device__ __forceinline__ float emit_sim(const v2f* zs, const v2f* accd,
                                          const v2f* accs) {
  constexpr float inv_n = 1.0f / (K * K);
  float mx[6], my[6];
  #pragma unroll
  for (int i = 0; i < 6; ++i) {
    mx[i] = ((i & 1) ? zs[i >> 1].y : zs[i >> 1].x) * inv_n;
    my[i] = ((i & 1) ? zs[3 + (i >> 1)].y : zs[3 + (i >> 1)].x) * inv_n;
  }
  float ax[21];
  {
    int t = 0;
    #pragma unroll
    for (int i = 0; i < 6; ++i)
      #pragma unroll
      for (int j = 0; j <= i; ++j) {
        const float e = (i == j) ? 1e-6f : 0.0f;
        ax[t] = gget(accd, accs, i, j) * inv_n - mx[i] * mx[j] + e;
        ++t;
      }
  }
  cholinv6(ax);
  float ay[21];
  {
    int t = 0;
    #pragma unroll
    for (int i = 0; i < 6; ++i)
      #pragma unroll
      for (int j = 0; j <= i; ++j) {
        const float e = (i == j) ? 1e-6f : 0.0f;
        ay[t] = gget(accd, accs, 6 + i, 6 + j) * inv_n - my[i] * my[j] + e;
        ++t;
      }
  }
  cholinv6(ay);
  float cxy[36];
  #pragma unroll
  for (int i = 0; i < 6; ++i)
    #pragma unroll
    for (int j = 0; j < 6; ++j)
      cxy[i * 6 + j] = fmaf(-mx[i], my[j], gget(accd, accs, 6 + j, i) * inv_n);
  float sim = 0.0f;
  #pragma unroll
  for (int i = 0; i < 6; ++i) {
    float di = 0.0f;
    #pragma unroll
    for (int j = 0; j <= i; ++j) {
      float inner = 0.0f;
      #pragma unroll
      for (int k = i; k < 6; ++k) inner += cxy[j * 6 + k] * ay[LT(k, i)];
      di += ax[LT(i, j)] * inner;
    }
    sim += fabsf(di);
  }
  return sim * (1.0f / 6.0f);
}

// One radius+batch per z. 16 tx x 16 strips, V=8 outputs per strip.
// Window for output row r = halo rows [r+4-R, r+4+R], cols [wc+4-R .. +R].
template <int R, int V>
__device__ __forceinline__ void run(const float* __restrict__ zb,
                                    float* __restrict__ out, int b, int ri) {
  constexpr int K = 2 * R + 1;
  constexpr int H = 512, W = 512;

  const int h0 = blockIdx.y * (16 * V);
  const int w0 = blockIdx.x * 16;
  const int tx = threadIdx.x & 15;
  const int g  = threadIdx.x >> 4;
  const int hbase = h0 + g * V;
  const int wc = w0 + tx;

  // first pixel (leftmost col) of the top window row, in halo coords
  const float* base = zb + (size_t)b * HB * RS
                    + (size_t)(hbase + 4 - R) * RS + (size_t)(wc + 4 - R) * PS;

  v2f zs[6]    = {};
  v2f accd[21] = {};
  v2f accs[21] = {};

  #pragma unroll 1
  for (int dy = 0; dy < K; ++dy)
    row_acc_g<K, true>(base + dy * RS, zs, accd, accs);

  out[((size_t)((b * H + hbase) * W + wc)) * 2 + ri] =
      emit_sim<K>(zs, accd, accs);

  #pragma unroll 1
  for (int s = 1; s < V; ++s) {
    row_acc_g<K, true >(base + (s + 2 * R) * RS, zs, accd, accs);  // entering
    row_acc_g<K, false>(base + (s - 1)     * RS, zs, accd, accs);  // leaving
    out[((size_t)((b * H + hbase + s) * W + wc)) * 2 + ri] =
        emit_sim<K>(zs, accd, accs);
  }
}

// z in {0,1}: r=2 batch z; z in {2,3}: r=4 batch z-2. No LDS, no barriers.
__global__ __launch_bounds__(256, 2)
void cca_v8(const float* __restrict__ zb, float* __restrict__ out) {
  const int z = blockIdx.z;
  if (z < 2) run<2, 8>(zb, out, z, 0);
  else       run<4, 8>(zb, out, z - 2, 1);
}

extern "C" void kernel_launch(void* const* d_in, const int* in_sizes, int n_in,
                              void* d_out, int out_size, void* d_ws, size_t ws_size,
                              hipStream_t stream) {
  const float* x = (const float*)d_in[0];
  const float* y = (const float*)d_in[1];
  float* out = (float*)d_out;
  float* zb  = (float*)d_ws;   // needs 2*520*520*12*4 B = 25.96 MB

  {
    const int n = 2 * HB * HB;
    prep_interleave<<<dim3((n + 255) / 256), dim3(256), 0, stream>>>(x, y, zb);
  }
  dim3 grid(512 / 16, 512 / (16 * 8), 4);   // 32 x 4 x 4 = 512 blocks
  cca_v8<<<grid, dim3(256), 0, stream>>>(zb, out);
}